// Round 1
// baseline (413.606 us; speedup 1.0000x reference)
//
#include <hip/hip_runtime.h>
#include <hip/hip_bf16.h>

// Problem constants
#define IN_DIM   256
#define CODE_LEN 128
#define MEM_LEN  65536
#define BETA     1.0f

// Output layout (floats): [0]=loss, [1..]=memory (MEM_LEN*CODE_LEN),
// then mem_data (MEM_LEN*IN_DIM), then mem_idx (MEM_LEN, as float)
#define OUT_MEM_OFF   1
#define OUT_MD_OFF    (1 + MEM_LEN*CODE_LEN)
#define OUT_IDX_OFF   (1 + MEM_LEN*CODE_LEN + MEM_LEN*IN_DIM)

// Workspace layout (bytes):
// 0    : float colsum[256]
// 1024 : float colsumsq[256]
// 2048 : float enc[128]
// 2560 : uint  loss_bits        (init 0xFFFFFFFF)
// 2568 : u64   idx_key          (init all-ones)
#define WS_COLSUM   0
#define WS_COLSQ    256
#define WS_ENC      512
#define WS_LOSS     640
#define WS_KEY      642   // u64 at float index 642 (byte 2568, 8B aligned)

// ---------------------------------------------------------------------------
// A: copy mem_data -> out, accumulate per-column sum & sumsq
// grid: 512 x 256. stride = 131072 float4 = 524288 floats (mult of 256) so
// each thread's 4 columns are fixed: col = (4*t) & 255.
__global__ void k_stats_copy(const float* __restrict__ mem_data,
                             float* __restrict__ out_md,
                             float* __restrict__ ws) {
    const int t = blockIdx.x * 256 + threadIdx.x;          // 0..131071
    const int total4 = (MEM_LEN * IN_DIM) / 4;             // 4194304
    float s0 = 0.f, s1 = 0.f, s2 = 0.f, s3 = 0.f;
    float q0 = 0.f, q1 = 0.f, q2 = 0.f, q3 = 0.f;
    for (int i = t; i < total4; i += 131072) {
        float4 v = ((const float4*)mem_data)[i];
        s0 += v.x; q0 += v.x * v.x;
        s1 += v.y; q1 += v.y * v.y;
        s2 += v.z; q2 += v.z * v.z;
        s3 += v.w; q3 += v.w * v.w;
        int base = i * 4;                                  // out region is +1 float: scalar stores
        out_md[base + 0] = v.x;
        out_md[base + 1] = v.y;
        out_md[base + 2] = v.z;
        out_md[base + 3] = v.w;
    }
    const int col = (t * 4) & 255;
    atomicAdd(&ws[WS_COLSUM + col + 0], s0);
    atomicAdd(&ws[WS_COLSUM + col + 1], s1);
    atomicAdd(&ws[WS_COLSUM + col + 2], s2);
    atomicAdd(&ws[WS_COLSUM + col + 3], s3);
    atomicAdd(&ws[WS_COLSQ + col + 0], q0);
    atomicAdd(&ws[WS_COLSQ + col + 1], q1);
    atomicAdd(&ws[WS_COLSQ + col + 2], q2);
    atomicAdd(&ws[WS_COLSQ + col + 3], q3);
}

// ---------------------------------------------------------------------------
// B: mean/std -> normalize x -> enc = new @ W^T + b.  1 block x 256 threads.
__global__ void k_enc(const float* __restrict__ x,
                      const float* __restrict__ W,
                      const float* __restrict__ b,
                      float* __restrict__ ws) {
    __shared__ float nrm[IN_DIM];
    const int t = threadIdx.x;
    float sum = ws[WS_COLSUM + t];
    float sq  = ws[WS_COLSQ + t];
    float mean = sum * (1.0f / MEM_LEN);
    float var  = (sq - sum * sum * (1.0f / MEM_LEN)) * (1.0f / (MEM_LEN - 1));
    var = fmaxf(var, 0.0f);
    float sd = sqrtf(var);
    nrm[t] = (sd == 0.0f) ? 0.0f : (x[t] - mean) / sd;
    __syncthreads();
    if (t < CODE_LEN) {
        float acc = b[t];
        const float* w = W + t * IN_DIM;
        #pragma unroll 8
        for (int d = 0; d < IN_DIM; ++d) acc += nrm[d] * w[d];
        ws[WS_ENC + t] = acc;
    }
}

// ---------------------------------------------------------------------------
// C: copy memory -> out, L1 distance per row, global min.
// 32 lanes per row (float4 each), 8 rows per 256-thread block pass.
__global__ void k_dist_copy(const float* __restrict__ memory,
                            float* __restrict__ out_mem,
                            float* __restrict__ ws) {
    __shared__ float4 es[32];
    __shared__ float red[256];
    const int t = threadIdx.x;
    if (t < 32) es[t] = ((const float4*)(ws + WS_ENC))[t];
    __syncthreads();
    const int lane = t & 31;
    const int grp  = t >> 5;
    const float4 e = es[lane];
    float localmin = 3.4e38f;
    for (int row = blockIdx.x * 8 + grp; row < MEM_LEN; row += gridDim.x * 8) {
        float4 m = ((const float4*)memory)[row * 32 + lane];
        float* o = out_mem + row * CODE_LEN + lane * 4;    // +1 float region: scalar stores
        o[0] = m.x; o[1] = m.y; o[2] = m.z; o[3] = m.w;
        float d = fabsf(m.x - e.x) + fabsf(m.y - e.y) +
                  fabsf(m.z - e.z) + fabsf(m.w - e.w);
        #pragma unroll
        for (int off = 16; off > 0; off >>= 1) d += __shfl_xor(d, off, 32);
        localmin = fminf(localmin, d);
    }
    red[t] = localmin;
    __syncthreads();
    for (int s = 128; s > 0; s >>= 1) {
        if (t < s) red[t] = fminf(red[t], red[t + s]);
        __syncthreads();
    }
    if (t == 0)
        atomicMin((unsigned int*)(ws + WS_LOSS), __float_as_uint(red[0]));
}

// ---------------------------------------------------------------------------
// D: copy mem_idx -> out (as float), argmin via packed (value,index) u64 min.
__global__ void k_idx(const int* __restrict__ mem_idx,
                      float* __restrict__ out_idx,
                      float* __restrict__ ws) {
    __shared__ unsigned long long red[256];
    const int t = blockIdx.x * blockDim.x + threadIdx.x;
    unsigned long long local = 0xFFFFFFFFFFFFFFFFull;
    for (int i = t; i < MEM_LEN; i += gridDim.x * blockDim.x) {
        int v = mem_idx[i];
        out_idx[i] = (float)v;
        unsigned long long key =
            (((unsigned long long)(unsigned int)(v ^ (int)0x80000000)) << 32) |
            (unsigned int)i;
        local = local < key ? local : key;
    }
    red[threadIdx.x] = local;
    __syncthreads();
    for (int s = 128; s > 0; s >>= 1) {
        if (threadIdx.x < s)
            red[threadIdx.x] = red[threadIdx.x] < red[threadIdx.x + s]
                                   ? red[threadIdx.x] : red[threadIdx.x + s];
        __syncthreads();
    }
    if (threadIdx.x == 0)
        atomicMin((unsigned long long*)(ws + WS_KEY), red[0]);
}

// ---------------------------------------------------------------------------
// E: write loss; conditional scatter update. 1 block x 256 threads.
__global__ void k_final(const float* __restrict__ x,
                        const int* __restrict__ count,
                        const float* __restrict__ ws,
                        float* __restrict__ d_out) {
    const int t = threadIdx.x;
    const float loss = __uint_as_float(((const unsigned int*)ws)[WS_LOSS]);
    if (t == 0) d_out[0] = loss;
    if (loss <= BETA) {
        unsigned long long key = *(const unsigned long long*)(ws + WS_KEY);
        unsigned int pos = (unsigned int)(key & 0xFFFFFFFFull);
        if (t < CODE_LEN)
            d_out[OUT_MEM_OFF + (size_t)pos * CODE_LEN + t] = ws[WS_ENC + t];
        d_out[OUT_MD_OFF + (size_t)pos * IN_DIM + t] = x[t];
        if (t == 0)
            d_out[OUT_IDX_OFF + pos] = (float)count[0];
    }
}

// ---------------------------------------------------------------------------
extern "C" void kernel_launch(void* const* d_in, const int* in_sizes, int n_in,
                              void* d_out, int out_size, void* d_ws, size_t ws_size,
                              hipStream_t stream) {
    const float* x        = (const float*)d_in[0];
    const float* memory   = (const float*)d_in[1];
    const float* mem_data = (const float*)d_in[2];
    const int*   mem_idx  = (const int*)d_in[3];
    const float* W        = (const float*)d_in[4];
    const float* b        = (const float*)d_in[5];
    const int*   count    = (const int*)d_in[6];
    float* out = (float*)d_out;
    float* ws  = (float*)d_ws;

    // init: colsum/colsumsq = 0, loss bits + argmin key = all-ones
    hipMemsetAsync(ws, 0, 2048, stream);
    hipMemsetAsync((char*)ws + 2560, 0xFF, 16, stream);

    k_stats_copy<<<512, 256, 0, stream>>>(mem_data, out + OUT_MD_OFF, ws);
    k_idx<<<64, 256, 0, stream>>>(mem_idx, out + OUT_IDX_OFF, ws);
    k_enc<<<1, 256, 0, stream>>>(x, W, b, ws);
    k_dist_copy<<<1024, 256, 0, stream>>>(memory, out + OUT_MEM_OFF, ws);
    k_final<<<1, 256, 0, stream>>>(x, count, ws, out);
}

// Round 2
// 226.718 us; speedup vs baseline: 1.8243x; 1.8243x over previous
//
#include <hip/hip_runtime.h>
#include <hip/hip_bf16.h>

// Problem constants
#define IN_DIM   256
#define CODE_LEN 128
#define MEM_LEN  65536
#define BETA     1.0f

// Output layout (floats): [0]=loss, [1..]=memory (MEM_LEN*CODE_LEN),
// then mem_data (MEM_LEN*IN_DIM), then mem_idx (MEM_LEN, as float)
#define OUT_MEM_OFF   1
#define OUT_MD_OFF    (1 + MEM_LEN*CODE_LEN)            // 8388609
#define OUT_IDX_OFF   (OUT_MD_OFF + MEM_LEN*IN_DIM)     // 25165825

// Workspace (float indices):
#define WS_COLSUM 0      // float[256]
#define WS_COLSQ  256    // float[256]
#define WS_ENC    512    // float[128]
#define WS_LOSS   640    // uint (init 0xFFFFFFFF)
#define WS_KEY    642    // u64 at byte 2568 (init all-ones)

#define MD_ELEMS  (MEM_LEN*IN_DIM)     // 16777216
#define MD_TILES  ((MD_ELEMS-4)/4)     // 4194303 full shifted tiles [4k+3..4k+6]
#define MEM_ELEMS (MEM_LEN*CODE_LEN)   // 8388608
#define MEM_STORE_TILES 2097151        // shifted tiles for memory copy

__device__ __forceinline__ float4 load4u(const float* p) {
    // 4B-aligned vector load; backend merges (unaligned global ok on gfx950)
    float4 v; v.x = p[0]; v.y = p[1]; v.z = p[2]; v.w = p[3]; return v;
}

// ---------------------------------------------------------------------------
// A: blocks [0,512): copy mem_data -> out (ALIGNED f4 stores, shifted tiles)
//    + per-column sum/sumsq with LDS reduction.
//    blocks [512,576): mem_idx copy + packed argmin.
__global__ __launch_bounds__(512, 4) void k_stats_copy(
        const float* __restrict__ mem_data,
        const int*   __restrict__ mem_idx,
        float* __restrict__ out,
        float* __restrict__ ws) {
    if (blockIdx.x >= 512) {
        __shared__ unsigned long long red[512];
        const int t = threadIdx.x;
        const int tid = (blockIdx.x - 512) * 512 + t;       // 0..32767
        unsigned long long local = ~0ull;
        #pragma unroll
        for (int rep = 0; rep < 2; ++rep) {
            int i = tid + rep * 32768;
            int v = mem_idx[i];
            out[OUT_IDX_OFF + i] = (float)v;
            unsigned long long key =
                (((unsigned long long)(unsigned int)(v ^ (int)0x80000000)) << 32)
                | (unsigned int)i;
            local = local < key ? local : key;
        }
        red[t] = local;
        __syncthreads();
        for (int s = 256; s > 0; s >>= 1) {
            if (t < s) { unsigned long long o = red[t + s]; if (o < red[t]) red[t] = o; }
            __syncthreads();
        }
        if (t == 0) atomicMin((unsigned long long*)(ws + WS_KEY), red[0]);
        return;
    }

    __shared__ float lsum[256], lsq[256];
    const int t = threadIdx.x;
    float* __restrict__ out_md = out + OUT_MD_OFF;
    const int t0 = blockIdx.x * 512 + t;                    // 0..262143
    float s0=0,s1=0,s2=0,s3=0,q0=0,q1=0,q2=0,q3=0;

    // stride 262144 tiles (mult of 64) => columns fixed per thread
    #pragma unroll 5
    for (int it = 0; it < 15; ++it) {
        const int k = t0 + it * 262144;
        const float* src = mem_data + 4*k + 3;
        float a0 = src[0], a1 = src[1], a2 = src[2], a3 = src[3];
        float4 v; v.x=a0; v.y=a1; v.z=a2; v.w=a3;
        *reinterpret_cast<float4*>(out_md + 4*k + 3) = v;   // 16B-aligned store
        s0 += a0; q0 += a0*a0;  s1 += a1; q1 += a1*a1;
        s2 += a2; q2 += a2*a2;  s3 += a3; q3 += a3*a3;
    }
    {   // 16th tile, predicated (only thread t0==262143 misses)
        const int k = t0 + 15 * 262144;
        if (k < MD_TILES) {
            const float* src = mem_data + 4*k + 3;
            float a0 = src[0], a1 = src[1], a2 = src[2], a3 = src[3];
            float4 v; v.x=a0; v.y=a1; v.z=a2; v.w=a3;
            *reinterpret_cast<float4*>(out_md + 4*k + 3) = v;
            s0 += a0; q0 += a0*a0;  s1 += a1; q1 += a1*a1;
            s2 += a2; q2 += a2*a2;  s3 += a3; q3 += a3*a3;
        }
    }

    if (t < 256) { lsum[t] = 0.f; lsq[t] = 0.f; }
    __syncthreads();
    const int c0 = (4*t0 + 3) & 255;
    atomicAdd(&lsum[c0],         s0);  atomicAdd(&lsq[c0],         q0);
    atomicAdd(&lsum[(c0+1)&255], s1);  atomicAdd(&lsq[(c0+1)&255], q1);
    atomicAdd(&lsum[(c0+2)&255], s2);  atomicAdd(&lsq[(c0+2)&255], q2);
    atomicAdd(&lsum[(c0+3)&255], s3);  atomicAdd(&lsq[(c0+3)&255], q3);
    __syncthreads();
    if (t < 256) {
        atomicAdd(&ws[WS_COLSUM + t], lsum[t]);
        atomicAdd(&ws[WS_COLSQ  + t], lsq[t]);
    }

    if (blockIdx.x == 0 && t == 0) {
        // edge elements 0,1,2 and last
        for (int e2 = 0; e2 < 3; ++e2) {
            float v = mem_data[e2];
            out_md[e2] = v;
            atomicAdd(&ws[WS_COLSUM + e2], v);
            atomicAdd(&ws[WS_COLSQ  + e2], v*v);
        }
        float v = mem_data[MD_ELEMS - 1];
        out_md[MD_ELEMS - 1] = v;
        atomicAdd(&ws[WS_COLSUM + 255], v);
        atomicAdd(&ws[WS_COLSQ  + 255], v*v);
    }
}

// ---------------------------------------------------------------------------
// B: mean/std -> normalize x -> enc = new @ W^T + b.  1 block x 256 threads.
__global__ void k_enc(const float* __restrict__ x,
                      const float* __restrict__ W,
                      const float* __restrict__ b,
                      float* __restrict__ ws) {
    __shared__ float nrm[IN_DIM];
    const int t = threadIdx.x;
    float sum = ws[WS_COLSUM + t];
    float sq  = ws[WS_COLSQ + t];
    float mean = sum * (1.0f / MEM_LEN);
    float var  = (sq - sum * sum * (1.0f / MEM_LEN)) * (1.0f / (MEM_LEN - 1));
    var = fmaxf(var, 0.0f);
    float sd = sqrtf(var);
    nrm[t] = (sd == 0.0f) ? 0.0f : (x[t] - mean) / sd;
    __syncthreads();
    if (t < CODE_LEN) {
        float acc = b[t];
        const float* w = W + t * IN_DIM;
        #pragma unroll 8
        for (int d = 0; d < IN_DIM; ++d) acc += nrm[d] * w[d];
        ws[WS_ENC + t] = acc;
    }
}

// ---------------------------------------------------------------------------
// C: memory copy (aligned f4 stores via shifted tiles, misaligned L1-hit
//    loads) + L1 distance per row (aligned loads), global min.
__global__ __launch_bounds__(256, 4) void k_dist_copy(
        const float* __restrict__ memory,
        float* __restrict__ out,
        float* __restrict__ ws) {
    __shared__ float4 es[32];
    __shared__ float red[256];
    const int t = threadIdx.x;
    if (t < 32) es[t] = ((const float4*)(ws + WS_ENC))[t];
    __syncthreads();
    const int lane = t & 31;
    const int grp  = t >> 5;
    const float4 e = es[lane];
    float* __restrict__ out_al = out + 4;   // = region idx 3; 16B-aligned
    float localmin = 3.4e38f;
    #pragma unroll 2
    for (int sweep = 0; sweep < 8; ++sweep) {
        const int row = sweep * 8192 + blockIdx.x * 8 + grp;   // exact cover
        const int i = row * 32 + lane;
        float4 m = ((const float4*)memory)[i];                 // aligned
        if (i < MEM_STORE_TILES) {
            float4 s = load4u(memory + 4*i + 3);               // L1 hit
            *reinterpret_cast<float4*>(out_al + 4*i) = s;      // aligned store
        }
        float d = fabsf(m.x-e.x) + fabsf(m.y-e.y) + fabsf(m.z-e.z) + fabsf(m.w-e.w);
        #pragma unroll
        for (int off = 16; off > 0; off >>= 1) d += __shfl_xor(d, off, 32);
        localmin = fminf(localmin, d);
    }
    red[t] = localmin;
    __syncthreads();
    for (int s2 = 128; s2 > 0; s2 >>= 1) {
        if (t < s2) red[t] = fminf(red[t], red[t + s2]);
        __syncthreads();
    }
    if (t == 0)
        atomicMin((unsigned int*)(ws + WS_LOSS), __float_as_uint(red[0]));
    if (blockIdx.x == 0 && t == 0) {
        float* om = out + OUT_MEM_OFF;
        om[0] = memory[0]; om[1] = memory[1]; om[2] = memory[2];
        om[MEM_ELEMS - 1] = memory[MEM_ELEMS - 1];
    }
}

// ---------------------------------------------------------------------------
// E: write loss; conditional scatter update. 1 block x 256 threads.
__global__ void k_final(const float* __restrict__ x,
                        const int* __restrict__ count,
                        const float* __restrict__ ws,
                        float* __restrict__ d_out) {
    const int t = threadIdx.x;
    const float loss = __uint_as_float(((const unsigned int*)ws)[WS_LOSS]);
    if (t == 0) d_out[0] = loss;
    if (loss <= BETA) {
        unsigned long long key = *(const unsigned long long*)(ws + WS_KEY);
        unsigned int pos = (unsigned int)(key & 0xFFFFFFFFull);
        if (t < CODE_LEN)
            d_out[OUT_MEM_OFF + (size_t)pos * CODE_LEN + t] = ws[WS_ENC + t];
        d_out[OUT_MD_OFF + (size_t)pos * IN_DIM + t] = x[t];
        if (t == 0)
            d_out[OUT_IDX_OFF + pos] = (float)count[0];
    }
}

// ---------------------------------------------------------------------------
extern "C" void kernel_launch(void* const* d_in, const int* in_sizes, int n_in,
                              void* d_out, int out_size, void* d_ws, size_t ws_size,
                              hipStream_t stream) {
    const float* x        = (const float*)d_in[0];
    const float* memory   = (const float*)d_in[1];
    const float* mem_data = (const float*)d_in[2];
    const int*   mem_idx  = (const int*)d_in[3];
    const float* W        = (const float*)d_in[4];
    const float* b        = (const float*)d_in[5];
    const int*   count    = (const int*)d_in[6];
    float* out = (float*)d_out;
    float* ws  = (float*)d_ws;

    hipMemsetAsync(ws, 0, 2048, stream);                   // colsum/colsq
    hipMemsetAsync((char*)ws + 2560, 0xFF, 16, stream);    // loss bits + key

    k_stats_copy<<<576, 512, 0, stream>>>(mem_data, mem_idx, out, ws);
    k_enc<<<1, 256, 0, stream>>>(x, W, b, ws);
    k_dist_copy<<<1024, 256, 0, stream>>>(memory, out, ws);
    k_final<<<1, 256, 0, stream>>>(x, count, ws, out);
}

// Round 4
// 225.953 us; speedup vs baseline: 1.8305x; 1.0034x over previous
//
#include <hip/hip_runtime.h>
#include <hip/hip_bf16.h>

// Problem constants
#define IN_DIM   256
#define CODE_LEN 128
#define MEM_LEN  65536
#define BETA     1.0f

// Output layout (floats): [0]=loss, [1..]=memory (MEM_LEN*CODE_LEN),
// then mem_data (MEM_LEN*IN_DIM), then mem_idx (MEM_LEN, as float)
#define OUT_MEM_OFF   1
#define OUT_MD_OFF    (1 + MEM_LEN*CODE_LEN)            // 8388609
#define OUT_IDX_OFF   (OUT_MD_OFF + MEM_LEN*IN_DIM)     // 25165825

// Workspace (float indices):
#define WS_COLSUM 0      // float[256]
#define WS_COLSQ  256    // float[256]
#define WS_ENC    512    // float[128]
#define WS_LOSS   640    // uint (init 0xFFFFFFFF)
#define WS_KEY    642    // u64 at byte 2568 (init all-ones)

#define MD_ELEMS  (MEM_LEN*IN_DIM)     // 16777216
#define MD_TILES  ((MD_ELEMS-4)/4)     // 4194303 shifted tiles [4k+3..4k+6]
#define MEM_ELEMS (MEM_LEN*CODE_LEN)   // 8388608
#define MEM_STORE_TILES 2097151        // shifted tiles for memory copy

// native clang vector type — required by __builtin_nontemporal_store
typedef float vfloat4 __attribute__((ext_vector_type(4)));

__device__ __forceinline__ vfloat4 load4u(const float* p) {
    vfloat4 v; v.x = p[0]; v.y = p[1]; v.z = p[2]; v.w = p[3]; return v;
}

// ---------------------------------------------------------------------------
// init: zero colsum/colsq, set loss/key sentinels (replaces 2 memset dispatches)
__global__ void k_init(float* __restrict__ ws) {
    const int t = threadIdx.x;            // 64 threads
    #pragma unroll
    for (int j = 0; j < 8; ++j) ws[t + j * 64] = 0.f;   // 512 floats
    if (t == 0) {
        ((unsigned int*)ws)[WS_LOSS] = 0xFFFFFFFFu;
        *((unsigned long long*)(ws + WS_KEY)) = ~0ull;
    }
}

// ---------------------------------------------------------------------------
// A: blocks [0,1024): copy mem_data -> out (aligned NT f4 stores, shifted
//    tiles, batched 8-deep loads for MLP) + per-column sum/sumsq.
//    blocks [1024,1088): mem_idx copy + packed argmin.
__global__ __launch_bounds__(256, 4) void k_stats_copy(
        const float* __restrict__ mem_data,
        const int*   __restrict__ mem_idx,
        float* __restrict__ out,
        float* __restrict__ ws) {
    const int t = threadIdx.x;

    if (blockIdx.x >= 1024) {
        __shared__ unsigned long long red[256];
        const int tid = (blockIdx.x - 1024) * 256 + t;      // 0..16383
        unsigned long long local = ~0ull;
        #pragma unroll
        for (int rep = 0; rep < 4; ++rep) {
            int i = tid + rep * 16384;
            int v = mem_idx[i];
            out[OUT_IDX_OFF + i] = (float)v;
            unsigned long long key =
                (((unsigned long long)(unsigned int)(v ^ (int)0x80000000)) << 32)
                | (unsigned int)i;
            local = local < key ? local : key;
        }
        red[t] = local;
        __syncthreads();
        for (int s = 128; s > 0; s >>= 1) {
            if (t < s) { unsigned long long o = red[t + s]; if (o < red[t]) red[t] = o; }
            __syncthreads();
        }
        if (t == 0) atomicMin((unsigned long long*)(ws + WS_KEY), red[0]);
        return;
    }

    __shared__ float lsum[256], lsq[256];
    float* __restrict__ out_md = out + OUT_MD_OFF;
    const int t0 = blockIdx.x * 256 + t;                    // 0..262143
    float s0=0,s1=0,s2=0,s3=0,q0=0,q1=0,q2=0,q3=0;

    // 16 tiles/thread, stride 262144 (mult of 64 => columns fixed per thread).
    // Two groups of 8: batch the loads, then the accumulate+NT-stores, so 8
    // dwordx4 loads are in flight before any store enters the vmcnt queue.
    #pragma unroll
    for (int g = 0; g < 2; ++g) {
        vfloat4 v[8];
        #pragma unroll
        for (int j = 0; j < 8; ++j) {
            const int k = t0 + (g * 8 + j) * 262144;
            if (k < MD_TILES) v[j] = load4u(mem_data + 4*k + 3);
            else              v[j] = (vfloat4){0.f, 0.f, 0.f, 0.f};
        }
        #pragma unroll
        for (int j = 0; j < 8; ++j) {
            const int k = t0 + (g * 8 + j) * 262144;
            if (k < MD_TILES) {
                __builtin_nontemporal_store(v[j],
                    reinterpret_cast<vfloat4*>(out_md + 4*k + 3));  // 16B-aligned
                s0 += v[j].x; q0 += v[j].x * v[j].x;
                s1 += v[j].y; q1 += v[j].y * v[j].y;
                s2 += v[j].z; q2 += v[j].z * v[j].z;
                s3 += v[j].w; q3 += v[j].w * v[j].w;
            }
        }
    }

    lsum[t] = 0.f; lsq[t] = 0.f;
    __syncthreads();
    const int c0 = (4*t0 + 3) & 255;
    atomicAdd(&lsum[c0],         s0);  atomicAdd(&lsq[c0],         q0);
    atomicAdd(&lsum[(c0+1)&255], s1);  atomicAdd(&lsq[(c0+1)&255], q1);
    atomicAdd(&lsum[(c0+2)&255], s2);  atomicAdd(&lsq[(c0+2)&255], q2);
    atomicAdd(&lsum[(c0+3)&255], s3);  atomicAdd(&lsq[(c0+3)&255], q3);
    __syncthreads();
    atomicAdd(&ws[WS_COLSUM + t], lsum[t]);
    atomicAdd(&ws[WS_COLSQ  + t], lsq[t]);

    if (blockIdx.x == 0 && t == 0) {
        for (int e = 0; e < 3; ++e) {
            float v = mem_data[e];
            out_md[e] = v;
            atomicAdd(&ws[WS_COLSUM + e], v);
            atomicAdd(&ws[WS_COLSQ  + e], v*v);
        }
        float v = mem_data[MD_ELEMS - 1];
        out_md[MD_ELEMS - 1] = v;
        atomicAdd(&ws[WS_COLSUM + 255], v);
        atomicAdd(&ws[WS_COLSQ  + 255], v*v);
    }
}

// ---------------------------------------------------------------------------
// B: mean/std -> normalize x -> enc = new @ W^T + b.  1 block x 256 threads.
__global__ void k_enc(const float* __restrict__ x,
                      const float* __restrict__ W,
                      const float* __restrict__ b,
                      float* __restrict__ ws) {
    __shared__ float nrm[IN_DIM];
    const int t = threadIdx.x;
    float sum = ws[WS_COLSUM + t];
    float sq  = ws[WS_COLSQ + t];
    float mean = sum * (1.0f / MEM_LEN);
    float var  = (sq - sum * sum * (1.0f / MEM_LEN)) * (1.0f / (MEM_LEN - 1));
    var = fmaxf(var, 0.0f);
    float sd = sqrtf(var);
    nrm[t] = (sd == 0.0f) ? 0.0f : (x[t] - mean) / sd;
    __syncthreads();
    if (t < CODE_LEN) {
        float acc = b[t];
        const float* w = W + t * IN_DIM;
        #pragma unroll 8
        for (int d = 0; d < IN_DIM; ++d) acc += nrm[d] * w[d];
        ws[WS_ENC + t] = acc;
    }
}

// ---------------------------------------------------------------------------
// C: memory copy (aligned NT f4 stores via shifted tiles, L1-hit shifted
//    re-loads) + L1 distance per row (aligned loads), global min.
//    Batched: 4 rows' loads issued, then stores+math.
__global__ __launch_bounds__(256, 4) void k_dist_copy(
        const float* __restrict__ memory,
        float* __restrict__ out,
        float* __restrict__ ws) {
    __shared__ vfloat4 es[32];
    __shared__ float red[256];
    const int t = threadIdx.x;
    if (t < 32) es[t] = ((const vfloat4*)(ws + WS_ENC))[t];
    __syncthreads();
    const int lane = t & 31;
    const int grp  = t >> 5;
    const vfloat4 e = es[lane];
    float* __restrict__ out_al = out + 4;   // region idx 3; 16B-aligned
    float localmin = 3.4e38f;
    #pragma unroll
    for (int half = 0; half < 2; ++half) {
        vfloat4 m[4], s[4];
        int idx[4];
        #pragma unroll
        for (int sw = 0; sw < 4; ++sw) {
            const int row = (half * 4 + sw) * 8192 + blockIdx.x * 8 + grp;
            const int i = row * 32 + lane;
            idx[sw] = i;
            m[sw] = ((const vfloat4*)memory)[i];             // aligned
            s[sw] = (i < MEM_STORE_TILES) ? load4u(memory + 4*i + 3)
                                          : (vfloat4){0.f, 0.f, 0.f, 0.f};
        }
        #pragma unroll
        for (int sw = 0; sw < 4; ++sw) {
            const int i = idx[sw];
            if (i < MEM_STORE_TILES)
                __builtin_nontemporal_store(s[sw],
                    reinterpret_cast<vfloat4*>(out_al + 4*i));
            float d = fabsf(m[sw].x-e.x) + fabsf(m[sw].y-e.y)
                    + fabsf(m[sw].z-e.z) + fabsf(m[sw].w-e.w);
            #pragma unroll
            for (int off = 16; off > 0; off >>= 1) d += __shfl_xor(d, off, 32);
            localmin = fminf(localmin, d);
        }
    }
    red[t] = localmin;
    __syncthreads();
    for (int s2 = 128; s2 > 0; s2 >>= 1) {
        if (t < s2) red[t] = fminf(red[t], red[t + s2]);
        __syncthreads();
    }
    if (t == 0)
        atomicMin((unsigned int*)(ws + WS_LOSS), __float_as_uint(red[0]));
    if (blockIdx.x == 0 && t == 0) {
        float* om = out + OUT_MEM_OFF;
        om[0] = memory[0]; om[1] = memory[1]; om[2] = memory[2];
        om[MEM_ELEMS - 1] = memory[MEM_ELEMS - 1];
    }
}

// ---------------------------------------------------------------------------
// E: write loss; conditional scatter update. 1 block x 256 threads.
__global__ void k_final(const float* __restrict__ x,
                        const int* __restrict__ count,
                        const float* __restrict__ ws,
                        float* __restrict__ d_out) {
    const int t = threadIdx.x;
    const float loss = __uint_as_float(((const unsigned int*)ws)[WS_LOSS]);
    if (t == 0) d_out[0] = loss;
    if (loss <= BETA) {
        unsigned long long key = *(const unsigned long long*)(ws + WS_KEY);
        unsigned int pos = (unsigned int)(key & 0xFFFFFFFFull);
        if (t < CODE_LEN)
            d_out[OUT_MEM_OFF + (size_t)pos * CODE_LEN + t] = ws[WS_ENC + t];
        d_out[OUT_MD_OFF + (size_t)pos * IN_DIM + t] = x[t];
        if (t == 0)
            d_out[OUT_IDX_OFF + pos] = (float)count[0];
    }
}

// ---------------------------------------------------------------------------
extern "C" void kernel_launch(void* const* d_in, const int* in_sizes, int n_in,
                              void* d_out, int out_size, void* d_ws, size_t ws_size,
                              hipStream_t stream) {
    const float* x        = (const float*)d_in[0];
    const float* memory   = (const float*)d_in[1];
    const float* mem_data = (const float*)d_in[2];
    const int*   mem_idx  = (const int*)d_in[3];
    const float* W        = (const float*)d_in[4];
    const float* b        = (const float*)d_in[5];
    const int*   count    = (const int*)d_in[6];
    float* out = (float*)d_out;
    float* ws  = (float*)d_ws;

    k_init<<<1, 64, 0, stream>>>(ws);
    k_stats_copy<<<1088, 256, 0, stream>>>(mem_data, mem_idx, out, ws);
    k_enc<<<1, 256, 0, stream>>>(x, W, b, ws);
    k_dist_copy<<<1024, 256, 0, stream>>>(memory, out, ws);
    k_final<<<1, 256, 0, stream>>>(x, count, ws, out);
}